// Round 1
// baseline (10090.510 us; speedup 1.0000x reference)
//
#include <hip/hip_runtime.h>

// Problem constants: B=32, T=1024, I=H=512, 2H=1024
#define NWG 64
#define T_STEPS 1024

typedef __bf16 bf8 __attribute__((ext_vector_type(8)));
typedef float  f4  __attribute__((ext_vector_type(4)));

__device__ __forceinline__ f4 mfma16(bf8 a, bf8 b, f4 c) {
    return __builtin_amdgcn_mfma_f32_16x16x32_bf16(a, b, c, 0, 0, 0);
}

__device__ __forceinline__ float sigf(float x)     { return 1.f / (1.f + __expf(-x)); }
__device__ __forceinline__ float tanhfast(float x) { return 1.f - 2.f / (1.f + __expf(2.f * x)); }

// ws layout (bytes):
//   [0,256)            : barrier counter (u32) + pad
//   [256, 65792)       : ring0  (2 slots x 32x512 bf16 = 65536 B)
//   [65792, 131328)    : ring1
//   [131328, 262400)   : final_c  (32 x 2 x 512 f32)
// d_out layout (f32 elems):
//   seg0 [0, 33554432)           : output copy 1  [B,T,2,H]
//   seg1 [33554432, 67108864)    : output copy 2
//   seg2 [67108864, 100663296)   : con; used as scratch during the run:
//        ti0  f32  [T][B][H] = 16777216 f32 at seg2+0
//        xbf  bf16 [T*B][H]  row r = t*32+b, after ti0
//        w0hi/w0lo bf16 [N][K] transposed W_in_0

// ---------------- init: zero ws control region, x -> bf16, W_in_0 -> [n][k] bf16 hi/lo
__global__ __launch_bounds__(256) void k_init(const float* __restrict__ x,
                                              const float* __restrict__ w_in0,
                                              __bf16* __restrict__ xbf,
                                              __bf16* __restrict__ w0hi,
                                              __bf16* __restrict__ w0lo,
                                              unsigned* __restrict__ wszero)
{
    size_t id = (size_t)blockIdx.x * 256 + threadIdx.x;
    size_t gs = (size_t)gridDim.x * 256;
    for (size_t i = id; i < 32832; i += gs) wszero[i] = 0u;   // cnt + rings
    for (size_t i = id; i < (size_t)16777216; i += gs) {
        size_t r = i >> 9, c = i & 511;
        size_t b = r & 31, t = r >> 5;
        xbf[i] = (__bf16)x[(((b << 10) + t) << 9) + c];
    }
    for (size_t i = id; i < (size_t)262144; i += gs) {
        size_t n = i >> 9, k = i & 511;
        float v = w_in0[(k << 9) + n];
        __bf16 h = (__bf16)v;
        w0hi[i] = h;
        w0lo[i] = (__bf16)(v - (float)h);
    }
}

// ---------------- pregemm: ti0[t*32+b][h] = x @ W_in_0 + b_in_0  (M=32768,N=512,K=512)
__global__ __launch_bounds__(256) void k_pregemm(const __bf16* __restrict__ xbf,
                                                 const __bf16* __restrict__ w0hi,
                                                 const __bf16* __restrict__ w0lo,
                                                 const float* __restrict__ b_in0,
                                                 float* __restrict__ ti0)
{
    int tid = threadIdx.x, lane = tid & 63, wid = tid >> 6;
    int wg = blockIdx.x;
    int mbase = (wg & 511) * 64 + wid * 16;   // 512 M-tiles of 64 rows, wave owns 16
    int nbase = (wg >> 9) * 128;              // 4 N-tiles of 128 cols
    int col = lane & 15, kgrp = lane >> 4;
    f4 acc[8];
#pragma unroll
    for (int i = 0; i < 8; ++i) acc[i] = (f4){0.f, 0.f, 0.f, 0.f};
    const __bf16* ap = xbf + (size_t)(mbase + col) * 512 + kgrp * 8;
    for (int kk = 0; kk < 16; ++kk) {
        bf8 a = *reinterpret_cast<const bf8*>(ap + kk * 32);
        const __bf16* wb = w0hi + (size_t)(nbase + col) * 512 + kk * 32 + kgrp * 8;
        const __bf16* wl = w0lo + (size_t)(nbase + col) * 512 + kk * 32 + kgrp * 8;
#pragma unroll
        for (int ct = 0; ct < 8; ++ct) {
            bf8 bh = *reinterpret_cast<const bf8*>(wb + (size_t)ct * 16 * 512);
            bf8 bl = *reinterpret_cast<const bf8*>(wl + (size_t)ct * 16 * 512);
            acc[ct] = mfma16(a, bh, acc[ct]);
            acc[ct] = mfma16(a, bl, acc[ct]);
        }
    }
#pragma unroll
    for (int ct = 0; ct < 8; ++ct) {
        int c = nbase + ct * 16 + col;
        float bias = b_in0[c];
#pragma unroll
        for (int r = 0; r < 4; ++r) {
            int row = mbase + kgrp * 4 + r;
            ti0[(size_t)row * 512 + c] = acc[ct][r] + bias;
        }
    }
}

// ---------------- persistent recurrence: 64 WGs, each owns 8 h-cols of both layers
__global__ __launch_bounds__(256) void k_recur(const float* __restrict__ wh0, const float* __restrict__ bh0g,
                                               const float* __restrict__ win1, const float* __restrict__ bin1g,
                                               const float* __restrict__ wh1, const float* __restrict__ bh1g,
                                               const float* __restrict__ ti0,
                                               float* __restrict__ out,
                                               unsigned* __restrict__ ws)
{
    __shared__ __bf16 sW[6][8192];     // Wh0 hi/lo, Wh1 hi/lo, Win1 hi/lo : [16 cols][512 k] swizzled
    __shared__ float  sB[3][16];
    __shared__ float  sTi1[32 * 8];

    unsigned* cnt = ws;
    __bf16* ring0 = (__bf16*)((char*)ws + 256);
    __bf16* ring1 = ring0 + 32768;
    float*  fc    = (float*)((char*)ws + 256 + 131072);

    int tid = threadIdx.x, lane = tid & 63, wid = tid >> 6;
    int wg = blockIdx.x;
    int h0 = wg * 8;
    int col = lane & 15, kgrp = lane >> 4;
    int bhalf = wid & 1;
    int rowA = bhalf * 16 + col;

    // load weight slices to LDS as bf16 hi/lo, XOR-swizzled for conflict-free ds_read_b128
    for (int i = tid; i < 8192; i += 256) {
        int cl = i & 15, k = i >> 4;
        int sw = (cl * 512 + k) ^ ((cl & 7) << 3);
        int cg = (cl < 8) ? (h0 + cl) : (512 + h0 + (cl - 8));
        float v0 = wh0[(size_t)k * 1024 + cg];
        __bf16 a0 = (__bf16)v0;
        sW[0][sw] = a0; sW[1][sw] = (__bf16)(v0 - (float)a0);
        float v1 = wh1[(size_t)k * 1024 + cg];
        __bf16 a1 = (__bf16)v1;
        sW[2][sw] = a1; sW[3][sw] = (__bf16)(v1 - (float)a1);
        float v2 = (cl < 8) ? win1[(size_t)k * 512 + h0 + cl] : 0.f;
        __bf16 a2 = (__bf16)v2;
        sW[4][sw] = a2; sW[5][sw] = (__bf16)(v2 - (float)a2);
    }
    if (tid < 16) {
        int cg = (tid < 8) ? (h0 + tid) : (512 + h0 + (tid - 8));
        sB[0][tid] = bh0g[cg];
        sB[1][tid] = bh1g[cg];
        sB[2][tid] = (tid < 8) ? bin1g[h0 + tid] : 0.f;
    }
    __syncthreads();

    float c0s[4] = {0.f, 0.f, 0.f, 0.f};
    float c1s[4] = {0.f, 0.f, 0.f, 0.f};

    for (int ph = 0; ph <= T_STEPS; ++ph) {
        int rdSlot = (ph + 1) & 1;
        f4 accg = {0.f, 0.f, 0.f, 0.f};
        f4 acct = {0.f, 0.f, 0.f, 0.f};
        if (wid < 2) {
            // part A: gates0(ph) and ti1(ph-1), both from m0n(ph-1)
            const __bf16* mp = ring0 + rdSlot * 16384 + (size_t)rowA * 512 + kgrp * 8;
#pragma unroll
            for (int kk = 0; kk < 16; ++kk) {
                bf8 a = *reinterpret_cast<const bf8*>(mp + kk * 32);
                int e = (col * 512 + kk * 32 + kgrp * 8) ^ ((col & 7) << 3);
                accg = mfma16(a, *reinterpret_cast<const bf8*>(&sW[0][e]), accg);
                accg = mfma16(a, *reinterpret_cast<const bf8*>(&sW[1][e]), accg);
                acct = mfma16(a, *reinterpret_cast<const bf8*>(&sW[4][e]), acct);
                acct = mfma16(a, *reinterpret_cast<const bf8*>(&sW[5][e]), acct);
            }
            if (col < 8) {
#pragma unroll
                for (int r = 0; r < 4; ++r) {
                    int b = bhalf * 16 + kgrp * 4 + r;
                    sTi1[b * 8 + col] = acct[r] + sB[2][col];
                }
            }
            if (ph < T_STEPS) {
                float g[4], go[4];
#pragma unroll
                for (int r = 0; r < 4; ++r) g[r] = accg[r] + sB[0][col];
#pragma unroll
                for (int r = 0; r < 4; ++r) go[r] = __shfl_xor(g[r], 8, 64);
                if (col < 8) {
                    int h = h0 + col;
#pragma unroll
                    for (int r = 0; r < 4; ++r) {
                        int b = bhalf * 16 + kgrp * 4 + r;
                        float retain = sigf(g[r]);
                        float merge  = sigf(go[r]);
                        float t0 = ti0[((size_t)ph * 32 + b) * 512 + h];
                        float cv = tanhfast(c0s[r] + retain * t0);
                        c0s[r] = cv;
                        float m0n = (1.f - merge) * t0 + merge * cv;
                        size_t ob = ((size_t)b * 1024 + ph) * 1024 + h;
                        out[ob] = m0n;
                        out[(size_t)33554432 + ob] = m0n;
                        ring0[(ph & 1) * 16384 + b * 512 + h] = (__bf16)m0n;
                    }
                }
            }
        } else if (ph >= 1) {
            // part B K-loop: gates1(ph-1) from m1n(ph-2)
            const __bf16* mp = ring1 + (ph & 1) * 16384 + (size_t)rowA * 512 + kgrp * 8;
#pragma unroll
            for (int kk = 0; kk < 16; ++kk) {
                bf8 a = *reinterpret_cast<const bf8*>(mp + kk * 32);
                int e = (col * 512 + kk * 32 + kgrp * 8) ^ ((col & 7) << 3);
                accg = mfma16(a, *reinterpret_cast<const bf8*>(&sW[2][e]), accg);
                accg = mfma16(a, *reinterpret_cast<const bf8*>(&sW[3][e]), accg);
            }
        }
        __syncthreads();   // sTi1 handoff
        if (wid >= 2 && ph >= 1) {
            int tB = ph - 1;
            float g[4], go[4];
#pragma unroll
            for (int r = 0; r < 4; ++r) g[r] = accg[r] + sB[1][col];
#pragma unroll
            for (int r = 0; r < 4; ++r) go[r] = __shfl_xor(g[r], 8, 64);
            if (col < 8) {
                int h = h0 + col;
#pragma unroll
                for (int r = 0; r < 4; ++r) {
                    int b = bhalf * 16 + kgrp * 4 + r;
                    float retain = sigf(g[r]);
                    float merge  = sigf(go[r]);
                    float t1 = sTi1[b * 8 + col];
                    float cv = tanhfast(c1s[r] + retain * t1);
                    c1s[r] = cv;
                    float m1n = (1.f - merge) * t1 + merge * cv;
                    size_t ob = ((size_t)b * 1024 + tB) * 1024 + 512 + h;
                    out[ob] = m1n;
                    out[(size_t)33554432 + ob] = m1n;
                    ring1[((ph + 1) & 1) * 16384 + b * 512 + h] = (__bf16)m1n;
                }
            }
        }
        // ---- grid barrier (monotonic counter, device scope) ----
        __syncthreads();
        if (tid == 0) {
            __threadfence();
            atomicAdd(cnt, 1u);
            unsigned tgt = (unsigned)(ph + 1) * NWG;
            while (__hip_atomic_load(cnt, __ATOMIC_RELAXED, __HIP_MEMORY_SCOPE_AGENT) < tgt) {
                __builtin_amdgcn_s_sleep(1);
            }
            __threadfence();
        }
        __syncthreads();
    }

    // final cell states
    if (col < 8) {
        int h = h0 + col;
        if (wid < 2) {
#pragma unroll
            for (int r = 0; r < 4; ++r) {
                int b = bhalf * 16 + kgrp * 4 + r;
                fc[((size_t)b * 2 + 0) * 512 + h] = c0s[r];
            }
        } else {
#pragma unroll
            for (int r = 0; r < 4; ++r) {
                int b = bhalf * 16 + kgrp * 4 + r;
                fc[((size_t)b * 2 + 1) * 512 + h] = c1s[r];
            }
        }
    }
}

// ---------------- finalize: broadcast final_c into seg2 (con)
__global__ __launch_bounds__(256) void k_final(const float* __restrict__ fc,
                                               float* __restrict__ seg2)
{
    size_t id = (size_t)blockIdx.x * 256 + threadIdx.x;
    size_t gs = (size_t)gridDim.x * 256;
    for (size_t i = id; i < (size_t)8388608; i += gs) {
        size_t flat = i * 4;
        int h = (int)(flat & 511);
        int l = (int)((flat >> 9) & 1);
        int b = (int)(flat >> 20);
        f4 v = *reinterpret_cast<const f4*>(&fc[((size_t)b * 2 + l) * 512 + h]);
        *reinterpret_cast<f4*>(&seg2[flat]) = v;
    }
}

extern "C" void kernel_launch(void* const* d_in, const int* in_sizes, int n_in,
                              void* d_out, int out_size, void* d_ws, size_t ws_size,
                              hipStream_t stream)
{
    const float* x     = (const float*)d_in[0];
    const float* w_in0 = (const float*)d_in[1];
    const float* b_in0 = (const float*)d_in[2];
    const float* wh0   = (const float*)d_in[3];
    const float* bh0   = (const float*)d_in[4];
    const float* win1  = (const float*)d_in[5];
    const float* bin1  = (const float*)d_in[6];
    const float* wh1   = (const float*)d_in[7];
    const float* bh1   = (const float*)d_in[8];
    float* out = (float*)d_out;

    float*  ti0  = out + (size_t)2 * 33554432;      // seg2 scratch
    __bf16* xbf  = (__bf16*)(ti0 + 16777216);
    __bf16* w0hi = xbf + 16777216;
    __bf16* w0lo = w0hi + 262144;

    k_init<<<1024, 256, 0, stream>>>(x, w_in0, xbf, w0hi, w0lo, (unsigned*)d_ws);
    k_pregemm<<<2048, 256, 0, stream>>>(xbf, w0hi, w0lo, b_in0, ti0);
    k_recur<<<NWG, 256, 0, stream>>>(wh0, bh0, win1, bin1, wh1, bh1, ti0, out, (unsigned*)d_ws);
    k_final<<<1024, 256, 0, stream>>>((const float*)((char*)d_ws + 256 + 131072),
                                      out + (size_t)2 * 33554432);
}